// Round 1
// baseline (7743.260 us; speedup 1.0000x reference)
//
#include <hip/hip_runtime.h>
#include <math.h>

#define NN 4096
#define NE 131072
#define DIM 256
#define NHEAD 8
#define HD 32

__device__ __forceinline__ float elu_f(float v){ return v > 0.f ? v : expm1f(v); }
__device__ __forceinline__ float gelu_f(float v){
  const float c = 0.7978845608028654f;
  float t = tanhf(c * (v + 0.044715f * v * v * v));
  return 0.5f * v * (1.f + t);
}

// ---------------- CSR build ----------------
__global__ void zero_counts(int* __restrict__ counts) {
  int i = blockIdx.x * 256 + threadIdx.x;
  if (i < NN) counts[i] = 0;
}

__global__ void count_edges(const int* __restrict__ ei, int* __restrict__ counts) {
  int e = blockIdx.x * 256 + threadIdx.x;
  if (e < NE) atomicAdd(&counts[ei[NE + e]], 1);
}

__global__ __launch_bounds__(1024) void scan_offsets(const int* __restrict__ counts,
                                                     int* __restrict__ offs,
                                                     int* __restrict__ cursor) {
  __shared__ int tmp[1024];
  int t = threadIdx.x;
  int base = t * 4;
  int c0 = counts[base], c1 = counts[base+1], c2 = counts[base+2], c3 = counts[base+3];
  int tsum = c0 + c1 + c2 + c3;
  tmp[t] = tsum;
  __syncthreads();
  for (int d = 1; d < 1024; d <<= 1) {
    int v = (t >= d) ? tmp[t - d] : 0;
    __syncthreads();
    tmp[t] += v;
    __syncthreads();
  }
  int excl = tmp[t] - tsum;
  offs[base]   = excl;           cursor[base]   = excl;
  offs[base+1] = excl + c0;      cursor[base+1] = excl + c0;
  offs[base+2] = excl + c0 + c1; cursor[base+2] = excl + c0 + c1;
  offs[base+3] = excl + c0 + c1 + c2; cursor[base+3] = excl + c0 + c1 + c2;
  if (t == 1023) offs[NN] = tmp[1023];
}

__global__ void scatter_edges(const int* __restrict__ ei, int* __restrict__ cursor,
                              int* __restrict__ esrc) {
  int e = blockIdx.x * 256 + threadIdx.x;
  if (e < NE) {
    int d = ei[NE + e];
    int pos = atomicAdd(&cursor[d], 1);
    esrc[pos] = ei[e];
  }
}

// block per node: out[n][c] = (1+eps)*x[n][c] + sum_{e in csr[n]} x[src_e][c]
__global__ __launch_bounds__(256) void gin_agg(const int* __restrict__ offs,
                                               const int* __restrict__ esrc,
                                               const float* __restrict__ x,
                                               const float* __restrict__ eps_p, int l,
                                               float* __restrict__ out) {
  int n = blockIdx.x, c = threadIdx.x;
  int e0 = offs[n], e1 = offs[n + 1];
  float acc = 0.f;
  for (int e = e0; e < e1; e++) acc += x[(size_t)esrc[e] * DIM + c];
  float eps = eps_p[l];
  out[(size_t)n * DIM + c] = (1.f + eps) * x[(size_t)n * DIM + c] + acc;
}

// ---------------- GEMM: C = act(A @ W^T + bias) ----------------
// A[M,K] row-major, W[Nn,K] row-major. M,Nn multiples of 64. ACT: 0 none,1 elu,2 gelu
template<int ACT>
__global__ __launch_bounds__(256) void gemm_bias_act(
    const float* __restrict__ A, const float* __restrict__ W,
    const float* __restrict__ bias, float* __restrict__ C,
    int M, int Nn, int K)
{
  __shared__ float As[16][64];
  __shared__ float Ws[16][64];
  int bn = blockIdx.x * 64, bm = blockIdx.y * 64;
  int t = threadIdx.x;
  int tc = t & 15, tr = t >> 4;
  int row = t >> 2;            // 0..63
  int kk4 = (t & 3) << 2;      // 0,4,8,12
  float acc[4][4] = {};
  const float* ap = A + (size_t)(bm + row) * K;
  const float* wp = W + (size_t)(bn + row) * K;

  for (int k0 = 0; k0 < K; k0 += 16) {
    int gk = k0 + kk4;
    float4 av, wv;
    if (gk + 3 < K) {
      av = *(const float4*)(ap + gk);
      wv = *(const float4*)(wp + gk);
    } else {
      float a0=0,a1=0,a2=0,a3=0, w0=0,w1=0,w2=0,w3=0;
      if (gk   < K) { a0 = ap[gk];   w0 = wp[gk];   }
      if (gk+1 < K) { a1 = ap[gk+1]; w1 = wp[gk+1]; }
      if (gk+2 < K) { a2 = ap[gk+2]; w2 = wp[gk+2]; }
      av = make_float4(a0,a1,a2,a3); wv = make_float4(w0,w1,w2,w3);
    }
    As[kk4+0][row] = av.x; As[kk4+1][row] = av.y; As[kk4+2][row] = av.z; As[kk4+3][row] = av.w;
    Ws[kk4+0][row] = wv.x; Ws[kk4+1][row] = wv.y; Ws[kk4+2][row] = wv.z; Ws[kk4+3][row] = wv.w;
    __syncthreads();
    #pragma unroll
    for (int kk = 0; kk < 16; kk++) {
      float a0 = As[kk][(tr<<2)+0], a1 = As[kk][(tr<<2)+1];
      float a2 = As[kk][(tr<<2)+2], a3 = As[kk][(tr<<2)+3];
      float4 b4 = *(const float4*)&Ws[kk][tc<<2];
      acc[0][0] += a0*b4.x; acc[0][1] += a0*b4.y; acc[0][2] += a0*b4.z; acc[0][3] += a0*b4.w;
      acc[1][0] += a1*b4.x; acc[1][1] += a1*b4.y; acc[1][2] += a1*b4.z; acc[1][3] += a1*b4.w;
      acc[2][0] += a2*b4.x; acc[2][1] += a2*b4.y; acc[2][2] += a2*b4.z; acc[2][3] += a2*b4.w;
      acc[3][0] += a3*b4.x; acc[3][1] += a3*b4.y; acc[3][2] += a3*b4.z; acc[3][3] += a3*b4.w;
    }
    __syncthreads();
  }

  #pragma unroll
  for (int i = 0; i < 4; i++) {
    int m = bm + (tr<<2) + i;
    int n0 = bn + (tc<<2);
    float4 o;
    o.x = acc[i][0] + bias[n0+0];
    o.y = acc[i][1] + bias[n0+1];
    o.z = acc[i][2] + bias[n0+2];
    o.w = acc[i][3] + bias[n0+3];
    if (ACT == 1) { o.x=elu_f(o.x); o.y=elu_f(o.y); o.z=elu_f(o.z); o.w=elu_f(o.w); }
    if (ACT == 2) { o.x=gelu_f(o.x); o.y=gelu_f(o.y); o.z=gelu_f(o.z); o.w=gelu_f(o.w); }
    *(float4*)(C + (size_t)m * Nn + n0) = o;
  }
}

// ---------------- LayerNorm(+act) + residual add: x += act(LN(in)*g+b) ----------------
template<int ACT>
__global__ __launch_bounds__(256) void ln_act_add(const float* __restrict__ in,
                                                  const float* __restrict__ g,
                                                  const float* __restrict__ b,
                                                  float* __restrict__ x) {
  int rowb = blockIdx.x;
  int c = threadIdx.x;
  float v = in[(size_t)rowb * DIM + c];
  float s = v, s2 = v * v;
  #pragma unroll
  for (int off = 32; off >= 1; off >>= 1) {
    s  += __shfl_xor(s,  off, 64);
    s2 += __shfl_xor(s2, off, 64);
  }
  __shared__ float ws1[4], ws2[4];
  int w = threadIdx.x >> 6, lane = threadIdx.x & 63;
  if (lane == 0) { ws1[w] = s; ws2[w] = s2; }
  __syncthreads();
  s  = ws1[0] + ws1[1] + ws1[2] + ws1[3];
  s2 = ws2[0] + ws2[1] + ws2[2] + ws2[3];
  float mean = s * (1.f / DIM);
  float var = s2 * (1.f / DIM) - mean * mean;
  float r = rsqrtf(var + 1e-5f);
  float o = (v - mean) * r * g[c] + b[c];
  if (ACT == 1) o = elu_f(o);
  x[(size_t)rowb * DIM + c] += o;
}

// ---------------- flash attention: one wave per (row, head) ----------------
// qkv [NN, 768]: q = cols 0..255, k = 256..511, v = 512..767; head h owns cols h*32..h*32+31
__global__ __launch_bounds__(256) void flash_attn(const float* __restrict__ qkv,
                                                  float* __restrict__ out) {
  int wid = (blockIdx.x * 256 + threadIdx.x) >> 6;   // global wave id
  int lane = threadIdx.x & 63;
  int w = threadIdx.x >> 6;
  int head = wid & (NHEAD - 1);
  int row = wid >> 3;
  const float scale = 0.17677669529663687f; // 1/sqrt(32)

  const float* qp = qkv + (size_t)row * 768 + head * HD;
  float qr[HD];
  #pragma unroll
  for (int c = 0; c < HD; c++) qr[c] = qp[c] * scale;

  float m = -1e30f, l = 0.f;
  float acc[HD];
  #pragma unroll
  for (int c = 0; c < HD; c++) acc[c] = 0.f;

  for (int kb = 0; kb < NN; kb += 64) {
    int kidx = kb + lane;
    const float* kp = qkv + (size_t)kidx * 768 + DIM + head * HD;
    float sdot = 0.f;
    #pragma unroll
    for (int c = 0; c < HD; c++) sdot += qr[c] * kp[c];
    // wave max
    float cm = sdot;
    #pragma unroll
    for (int off = 32; off >= 1; off >>= 1) cm = fmaxf(cm, __shfl_xor(cm, off, 64));
    float nm = fmaxf(m, cm);
    float f = __expf(m - nm);
    float p = __expf(sdot - nm);
    float ps = p;
    #pragma unroll
    for (int off = 32; off >= 1; off >>= 1) ps += __shfl_xor(ps, off, 64);
    l = l * f + ps;
    m = nm;
    const float* vp = qkv + (size_t)kidx * 768 + 2 * DIM + head * HD;
    #pragma unroll
    for (int c = 0; c < HD; c++) acc[c] = acc[c] * f + p * vp[c];
  }

  // cross-lane reduction of the 32 accumulators via LDS
  __shared__ float red[4][64][HD + 1];
  #pragma unroll
  for (int c = 0; c < HD; c++) red[w][lane][c] = acc[c];
  __syncthreads();
  if (lane < HD) {
    float s2 = 0.f;
    #pragma unroll 8
    for (int j = 0; j < 64; j++) s2 += red[w][j][lane];
    out[(size_t)row * DIM + head * HD + lane] = s2 / l;
  }
}

// ---------------- tiny head: out[4096,5] ----------------
__global__ void head2_kernel(const float* __restrict__ e, const float* __restrict__ w,
                             const float* __restrict__ b, float* __restrict__ out) {
  int idx = blockIdx.x * 256 + threadIdx.x;
  if (idx >= NN * 5) return;
  int rowi = idx / 5, col = idx % 5;
  float s = b[col];
  const float* ep = e + (size_t)rowi * 128;
  const float* wp = w + (size_t)col * 128;
  #pragma unroll 16
  for (int k = 0; k < 128; k++) s += ep[k] * wp[k];
  out[idx] = s;
}

extern "C" void kernel_launch(void* const* d_in, const int* in_sizes, int n_in,
                              void* d_out, int out_size, void* d_ws, size_t ws_size,
                              hipStream_t stream) {
  const float* x_in   = (const float*)d_in[0];
  const int*   ei     = (const int*)  d_in[1];
  const float* in_w   = (const float*)d_in[2];
  const float* in_b   = (const float*)d_in[3];
  const float* head_w1= (const float*)d_in[4];
  const float* head_b1= (const float*)d_in[5];
  const float* head_w2= (const float*)d_in[6];
  const float* head_b2= (const float*)d_in[7];
  const float* mlp_w1 = (const float*)d_in[8];
  const float* mlp_b1 = (const float*)d_in[9];
  const float* mlp_w2 = (const float*)d_in[10];
  const float* mlp_b2 = (const float*)d_in[11];
  const float* gin_eps= (const float*)d_in[12];
  const float* ln1_g  = (const float*)d_in[13];
  const float* ln1_b  = (const float*)d_in[14];
  const float* attn_in_w = (const float*)d_in[15];
  const float* attn_in_b = (const float*)d_in[16];
  const float* attn_out_w= (const float*)d_in[17];
  const float* attn_out_b= (const float*)d_in[18];
  const float* ln2_g  = (const float*)d_in[19];
  const float* ln2_b  = (const float*)d_in[20];
  const float* ffn_w1 = (const float*)d_in[21];
  const float* ffn_b1 = (const float*)d_in[22];
  const float* ffn_w2 = (const float*)d_in[23];
  const float* ffn_b2 = (const float*)d_in[24];
  const float* ln3_g  = (const float*)d_in[25];
  const float* ln3_b  = (const float*)d_in[26];

  float* ws = (float*)d_ws;
  float* x   = ws;                                  // [NN,256]
  float* tb  = x   + (size_t)NN * DIM;              // [NN,768] (qkv / mlp-hidden / ffn-hidden)
  float* t2  = tb  + (size_t)NN * 768;              // [NN,256]
  float* agg = t2  + (size_t)NN * DIM;              // [NN,256]
  float* att = agg + (size_t)NN * DIM;              // [NN,256]
  float* he  = att + (size_t)NN * DIM;              // [NN,128]
  int* counts = (int*)(he + (size_t)NN * 128);
  int* offs   = counts + NN;       // NN+1
  int* cursor = offs + NN + 1;
  int* esrc   = cursor + NN;       // NE

  // CSR build (edges identical for both layers)
  zero_counts<<<16, 256, 0, stream>>>(counts);
  count_edges<<<NE / 256, 256, 0, stream>>>(ei, counts);
  scan_offsets<<<1, 1024, 0, stream>>>(counts, offs, cursor);
  scatter_edges<<<NE / 256, 256, 0, stream>>>(ei, cursor, esrc);

  // input projection: x = elu(x_in @ in_w^T + in_b)   [4096,72] -> [4096,256]
  gemm_bias_act<1><<<dim3(DIM/64, NN/64), 256, 0, stream>>>(x_in, in_w, in_b, x, NN, DIM, 72);

  for (int l = 0; l < 2; l++) {
    // GIN
    gin_agg<<<NN, 256, 0, stream>>>(offs, esrc, x, gin_eps, l, agg);
    gemm_bias_act<1><<<dim3(4, 64), 256, 0, stream>>>(agg, mlp_w1 + (size_t)l*DIM*DIM,
                                                      mlp_b1 + l*DIM, tb, NN, DIM, DIM);
    gemm_bias_act<0><<<dim3(4, 64), 256, 0, stream>>>(tb, mlp_w2 + (size_t)l*DIM*DIM,
                                                      mlp_b2 + l*DIM, t2, NN, DIM, DIM);
    ln_act_add<1><<<NN, 256, 0, stream>>>(t2, ln1_g + l*DIM, ln1_b + l*DIM, x);

    // attention
    gemm_bias_act<0><<<dim3(12, 64), 256, 0, stream>>>(x, attn_in_w + (size_t)l*768*DIM,
                                                       attn_in_b + l*768, tb, NN, 768, DIM);
    flash_attn<<<NN * NHEAD / 4, 256, 0, stream>>>(tb, att);
    gemm_bias_act<0><<<dim3(4, 64), 256, 0, stream>>>(att, attn_out_w + (size_t)l*DIM*DIM,
                                                      attn_out_b + l*DIM, t2, NN, DIM, DIM);
    ln_act_add<0><<<NN, 256, 0, stream>>>(t2, ln2_g + l*DIM, ln2_b + l*DIM, x);

    // FFN
    gemm_bias_act<2><<<dim3(8, 64), 256, 0, stream>>>(x, ffn_w1 + (size_t)l*512*DIM,
                                                      ffn_b1 + l*512, tb, NN, 512, DIM);
    gemm_bias_act<0><<<dim3(4, 64), 256, 0, stream>>>(tb, ffn_w2 + (size_t)l*DIM*512,
                                                      ffn_b2 + l*DIM, t2, NN, DIM, 512);
    ln_act_add<0><<<NN, 256, 0, stream>>>(t2, ln3_g + l*DIM, ln3_b + l*DIM, x);
  }

  // head
  gemm_bias_act<1><<<dim3(2, 64), 256, 0, stream>>>(x, head_w1, head_b1, he, NN, 128, DIM);
  head2_kernel<<<(NN * 5 + 255) / 256, 256, 0, stream>>>(he, head_w2, head_b2, (float*)d_out);
}

// Round 2
// 676.060 us; speedup vs baseline: 11.4535x; 11.4535x over previous
//
#include <hip/hip_runtime.h>
#include <math.h>

#define NN 4096
#define NE 131072
#define DIM 256
#define NHEAD 8
#define HD 32

typedef __attribute__((ext_vector_type(8))) short short8v;
typedef __attribute__((ext_vector_type(4))) float f32x4;
#define MFMA16(a, b, c) __builtin_amdgcn_mfma_f32_16x16x32_bf16(a, b, c, 0, 0, 0)

__device__ __forceinline__ float elu_f(float v){ return v > 0.f ? v : expm1f(v); }
__device__ __forceinline__ float gelu_f(float v){
  const float c = 0.7978845608028654f;
  float t = tanhf(c * (v + 0.044715f * v * v * v));
  return 0.5f * v * (1.f + t);
}
__device__ __forceinline__ unsigned short f2bf(float f) {
  unsigned int u = __builtin_bit_cast(unsigned int, f);
  u += 0x7FFFu + ((u >> 16) & 1u);
  return (unsigned short)(u >> 16);
}

// ---------------- CSR build ----------------
__global__ void zero_counts(int* __restrict__ counts) {
  int i = blockIdx.x * 256 + threadIdx.x;
  if (i < NN) counts[i] = 0;
}

__global__ void count_edges(const int* __restrict__ ei, int* __restrict__ counts) {
  int e = blockIdx.x * 256 + threadIdx.x;
  if (e < NE) atomicAdd(&counts[ei[NE + e]], 1);
}

__global__ __launch_bounds__(1024) void scan_offsets(const int* __restrict__ counts,
                                                     int* __restrict__ offs,
                                                     int* __restrict__ cursor) {
  __shared__ int tmp[1024];
  int t = threadIdx.x;
  int base = t * 4;
  int c0 = counts[base], c1 = counts[base+1], c2 = counts[base+2], c3 = counts[base+3];
  int tsum = c0 + c1 + c2 + c3;
  tmp[t] = tsum;
  __syncthreads();
  for (int d = 1; d < 1024; d <<= 1) {
    int v = (t >= d) ? tmp[t - d] : 0;
    __syncthreads();
    tmp[t] += v;
    __syncthreads();
  }
  int excl = tmp[t] - tsum;
  offs[base]   = excl;           cursor[base]   = excl;
  offs[base+1] = excl + c0;      cursor[base+1] = excl + c0;
  offs[base+2] = excl + c0 + c1; cursor[base+2] = excl + c0 + c1;
  offs[base+3] = excl + c0 + c1 + c2; cursor[base+3] = excl + c0 + c1 + c2;
  if (t == 1023) offs[NN] = tmp[1023];
}

__global__ void scatter_edges(const int* __restrict__ ei, int* __restrict__ cursor,
                              int* __restrict__ esrc) {
  int e = blockIdx.x * 256 + threadIdx.x;
  if (e < NE) {
    int d = ei[NE + e];
    int pos = atomicAdd(&cursor[d], 1);
    esrc[pos] = ei[e];
  }
}

// block per node: out[n][c] = (1+eps)*x[n][c] + sum_{e in csr[n]} x[src_e][c]
__global__ __launch_bounds__(256) void gin_agg(const int* __restrict__ offs,
                                               const int* __restrict__ esrc,
                                               const float* __restrict__ x,
                                               const float* __restrict__ eps_p, int l,
                                               float* __restrict__ out) {
  int n = blockIdx.x, c = threadIdx.x;
  int e0 = offs[n], e1 = offs[n + 1];
  float acc = 0.f;
  for (int e = e0; e < e1; e++) acc += x[(size_t)esrc[e] * DIM + c];
  float eps = eps_p[l];
  out[(size_t)n * DIM + c] = (1.f + eps) * x[(size_t)n * DIM + c] + acc;
}

// ---------------- GEMM: C = act(A @ W^T + bias) (fp32) ----------------
template<int ACT>
__global__ __launch_bounds__(256) void gemm_bias_act(
    const float* __restrict__ A, const float* __restrict__ W,
    const float* __restrict__ bias, float* __restrict__ C,
    int M, int Nn, int K)
{
  __shared__ float As[16][64];
  __shared__ float Ws[16][64];
  int bn = blockIdx.x * 64, bm = blockIdx.y * 64;
  int t = threadIdx.x;
  int tc = t & 15, tr = t >> 4;
  int row = t >> 2;            // 0..63
  int kk4 = (t & 3) << 2;      // 0,4,8,12
  float acc[4][4] = {};
  const float* ap = A + (size_t)(bm + row) * K;
  const float* wp = W + (size_t)(bn + row) * K;

  for (int k0 = 0; k0 < K; k0 += 16) {
    int gk = k0 + kk4;
    float4 av, wv;
    if (gk + 3 < K) {
      av = *(const float4*)(ap + gk);
      wv = *(const float4*)(wp + gk);
    } else {
      float a0=0,a1=0,a2=0,a3=0, w0=0,w1=0,w2=0,w3=0;
      if (gk   < K) { a0 = ap[gk];   w0 = wp[gk];   }
      if (gk+1 < K) { a1 = ap[gk+1]; w1 = wp[gk+1]; }
      if (gk+2 < K) { a2 = ap[gk+2]; w2 = wp[gk+2]; }
      av = make_float4(a0,a1,a2,a3); wv = make_float4(w0,w1,w2,w3);
    }
    As[kk4+0][row] = av.x; As[kk4+1][row] = av.y; As[kk4+2][row] = av.z; As[kk4+3][row] = av.w;
    Ws[kk4+0][row] = wv.x; Ws[kk4+1][row] = wv.y; Ws[kk4+2][row] = wv.z; Ws[kk4+3][row] = wv.w;
    __syncthreads();
    #pragma unroll
    for (int kk = 0; kk < 16; kk++) {
      float a0 = As[kk][(tr<<2)+0], a1 = As[kk][(tr<<2)+1];
      float a2 = As[kk][(tr<<2)+2], a3 = As[kk][(tr<<2)+3];
      float4 b4 = *(const float4*)&Ws[kk][tc<<2];
      acc[0][0] += a0*b4.x; acc[0][1] += a0*b4.y; acc[0][2] += a0*b4.z; acc[0][3] += a0*b4.w;
      acc[1][0] += a1*b4.x; acc[1][1] += a1*b4.y; acc[1][2] += a1*b4.z; acc[1][3] += a1*b4.w;
      acc[2][0] += a2*b4.x; acc[2][1] += a2*b4.y; acc[2][2] += a2*b4.z; acc[2][3] += a2*b4.w;
      acc[3][0] += a3*b4.x; acc[3][1] += a3*b4.y; acc[3][2] += a3*b4.z; acc[3][3] += a3*b4.w;
    }
    __syncthreads();
  }

  #pragma unroll
  for (int i = 0; i < 4; i++) {
    int m = bm + (tr<<2) + i;
    int n0 = bn + (tc<<2);
    float4 o;
    o.x = acc[i][0] + bias[n0+0];
    o.y = acc[i][1] + bias[n0+1];
    o.z = acc[i][2] + bias[n0+2];
    o.w = acc[i][3] + bias[n0+3];
    if (ACT == 1) { o.x=elu_f(o.x); o.y=elu_f(o.y); o.z=elu_f(o.z); o.w=elu_f(o.w); }
    if (ACT == 2) { o.x=gelu_f(o.x); o.y=gelu_f(o.y); o.z=gelu_f(o.z); o.w=gelu_f(o.w); }
    *(float4*)(C + (size_t)m * Nn + n0) = o;
  }
}

// ---------------- LayerNorm(+act) + residual add ----------------
template<int ACT>
__global__ __launch_bounds__(256) void ln_act_add(const float* __restrict__ in,
                                                  const float* __restrict__ g,
                                                  const float* __restrict__ b,
                                                  float* __restrict__ x) {
  int rowb = blockIdx.x;
  int c = threadIdx.x;
  float v = in[(size_t)rowb * DIM + c];
  float s = v, s2 = v * v;
  #pragma unroll
  for (int off = 32; off >= 1; off >>= 1) {
    s  += __shfl_xor(s,  off, 64);
    s2 += __shfl_xor(s2, off, 64);
  }
  __shared__ float ws1[4], ws2[4];
  int w = threadIdx.x >> 6, lane = threadIdx.x & 63;
  if (lane == 0) { ws1[w] = s; ws2[w] = s2; }
  __syncthreads();
  s  = ws1[0] + ws1[1] + ws1[2] + ws1[3];
  s2 = ws2[0] + ws2[1] + ws2[2] + ws2[3];
  float mean = s * (1.f / DIM);
  float var = s2 * (1.f / DIM) - mean * mean;
  float r = rsqrtf(var + 1e-5f);
  float o = (v - mean) * r * g[c] + b[c];
  if (ACT == 1) o = elu_f(o);
  x[(size_t)rowb * DIM + c] += o;
}

// ---------------- qkv f32 -> bf16 (Q scaled by 1/sqrt(HD)) ----------------
__global__ __launch_bounds__(256) void qkv_convert(const float* __restrict__ tb,
                                                   unsigned short* __restrict__ qkvb) {
  int row = blockIdx.x;
  int c = threadIdx.x * 2;   // 0..510 -> covers Q (0..255) and K (256..511)
  float2 v = *(const float2*)(tb + (size_t)row * 768 + c);
  if (c < 256) { v.x *= 0.17677669529663687f; v.y *= 0.17677669529663687f; }
  unsigned int pack = (unsigned int)f2bf(v.x) | ((unsigned int)f2bf(v.y) << 16);
  *(unsigned int*)(qkvb + (size_t)row * 768 + c) = pack;
}

// ---------------- V transpose: qkv[:,512+h*32+d] -> VT[h][d][n] bf16 ----------------
__global__ __launch_bounds__(256) void vt_transpose(const float* __restrict__ tb,
                                                    unsigned short* __restrict__ VT) {
  __shared__ float lds[128][33];
  int h = blockIdx.y;
  int nb = blockIdx.x * 128;
  int tid = threadIdx.x;
  int r8 = tid >> 5, d = tid & 31;
  #pragma unroll
  for (int i = 0; i < 16; i++) {
    int n = i * 8 + r8;
    lds[n][d] = tb[(size_t)(nb + n) * 768 + 512 + h * 32 + d];
  }
  __syncthreads();
  int dd = tid >> 7, j = tid & 127;
  #pragma unroll
  for (int i = 0; i < 16; i++) {
    int d2 = i * 2 + dd;
    VT[((size_t)h * 32 + d2) * 4096 + nb + j] = f2bf(lds[j][d2]);
  }
}

// ---------------- MFMA flash attention ----------------
// qkvb [NN][768] bf16 (Q pre-scaled), VT [8][32][NN] bf16, out [NN][256] f32
// block: 4 waves, wave w handles q rows [blockIdx.x*64 + w*16, +16), head = blockIdx.y
__global__ __launch_bounds__(256) void attn_mfma(const unsigned short* __restrict__ qkvb,
                                                 const unsigned short* __restrict__ VT,
                                                 float* __restrict__ out) {
  __shared__ unsigned short plds[4][16][72];   // per-wave P tile [16q][64k], rows 144B (16B-aligned)
  int tid = threadIdx.x;
  int w = tid >> 6, lane = tid & 63;
  int lo = lane & 15, g = lane >> 4;
  int h = blockIdx.y;
  int qb = blockIdx.x * 64 + w * 16;

  // Q A-frag: row = qb+lo, k(dim) = 8g..8g+7  (contiguous bf16)
  short8v qf = *(const short8v*)(qkvb + (size_t)(qb + lo) * 768 + h * 32 + 8 * g);

  f32x4 acc0 = {0.f, 0.f, 0.f, 0.f};
  f32x4 acc1 = {0.f, 0.f, 0.f, 0.f};
  float mr[4] = {-1e30f, -1e30f, -1e30f, -1e30f};
  float lr[4] = {0.f, 0.f, 0.f, 0.f};

  const unsigned short* Kb = qkvb + 256 + h * 32 + 8 * g;
  const unsigned short* Vb = VT + (size_t)h * 32 * 4096 + 8 * g;
  const f32x4 zf = {0.f, 0.f, 0.f, 0.f};

  for (int kb = 0; kb < NN; kb += 64) {
    // S tiles: S[q][k] for k sub-tiles of 16
    short8v kf0 = *(const short8v*)(Kb + (size_t)(kb +  0 + lo) * 768);
    short8v kf1 = *(const short8v*)(Kb + (size_t)(kb + 16 + lo) * 768);
    short8v kf2 = *(const short8v*)(Kb + (size_t)(kb + 32 + lo) * 768);
    short8v kf3 = *(const short8v*)(Kb + (size_t)(kb + 48 + lo) * 768);
    f32x4 s0 = MFMA16(qf, kf0, zf);
    f32x4 s1 = MFMA16(qf, kf1, zf);
    f32x4 s2 = MFMA16(qf, kf2, zf);
    f32x4 s3 = MFMA16(qf, kf3, zf);

    #pragma unroll
    for (int r = 0; r < 4; r++) {
      float t = fmaxf(fmaxf(s0[r], s1[r]), fmaxf(s2[r], s3[r]));
      t = fmaxf(t, __shfl_xor(t, 1, 64));
      t = fmaxf(t, __shfl_xor(t, 2, 64));
      t = fmaxf(t, __shfl_xor(t, 4, 64));
      t = fmaxf(t, __shfl_xor(t, 8, 64));
      float nm = fmaxf(mr[r], t);
      float f = __expf(mr[r] - nm);
      mr[r] = nm;
      float p0 = __expf(s0[r] - nm), p1 = __expf(s1[r] - nm);
      float p2 = __expf(s2[r] - nm), p3 = __expf(s3[r] - nm);
      lr[r] = lr[r] * f + (p0 + p1 + p2 + p3);
      acc0[r] *= f; acc1[r] *= f;
      int q = 4 * g + r;
      plds[w][q][lo]      = f2bf(p0);
      plds[w][q][lo + 16] = f2bf(p1);
      plds[w][q][lo + 32] = f2bf(p2);
      plds[w][q][lo + 48] = f2bf(p3);
    }

    // PV: A = P[16q][64k] (2 frags), B = VT[d][k] (2 d-tiles x 2 k-halves)
    short8v pa0 = *(const short8v*)&plds[w][lo][ 0 + 8 * g];
    short8v pa1 = *(const short8v*)&plds[w][lo][32 + 8 * g];
    short8v vf00 = *(const short8v*)(Vb + (size_t)(lo)      * 4096 + kb);
    short8v vf01 = *(const short8v*)(Vb + (size_t)(lo)      * 4096 + kb + 32);
    short8v vf10 = *(const short8v*)(Vb + (size_t)(lo + 16) * 4096 + kb);
    short8v vf11 = *(const short8v*)(Vb + (size_t)(lo + 16) * 4096 + kb + 32);
    acc0 = MFMA16(pa0, vf00, acc0);
    acc0 = MFMA16(pa1, vf01, acc0);
    acc1 = MFMA16(pa0, vf10, acc1);
    acc1 = MFMA16(pa1, vf11, acc1);
  }

  #pragma unroll
  for (int r = 0; r < 4; r++) {
    float t = lr[r];
    t += __shfl_xor(t, 1, 64);
    t += __shfl_xor(t, 2, 64);
    t += __shfl_xor(t, 4, 64);
    t += __shfl_xor(t, 8, 64);
    float inv = 1.f / t;
    int q = qb + 4 * g + r;
    out[(size_t)q * DIM + h * 32 + lo]      = acc0[r] * inv;
    out[(size_t)q * DIM + h * 32 + 16 + lo] = acc1[r] * inv;
  }
}

// ---------------- tiny head: out[4096,5] ----------------
__global__ void head2_kernel(const float* __restrict__ e, const float* __restrict__ w,
                             const float* __restrict__ b, float* __restrict__ out) {
  int idx = blockIdx.x * 256 + threadIdx.x;
  if (idx >= NN * 5) return;
  int rowi = idx / 5, col = idx % 5;
  float s = b[col];
  const float* ep = e + (size_t)rowi * 128;
  const float* wp = w + (size_t)col * 128;
  #pragma unroll 16
  for (int k = 0; k < 128; k++) s += ep[k] * wp[k];
  out[idx] = s;
}

extern "C" void kernel_launch(void* const* d_in, const int* in_sizes, int n_in,
                              void* d_out, int out_size, void* d_ws, size_t ws_size,
                              hipStream_t stream) {
  const float* x_in   = (const float*)d_in[0];
  const int*   ei     = (const int*)  d_in[1];
  const float* in_w   = (const float*)d_in[2];
  const float* in_b   = (const float*)d_in[3];
  const float* head_w1= (const float*)d_in[4];
  const float* head_b1= (const float*)d_in[5];
  const float* head_w2= (const float*)d_in[6];
  const float* head_b2= (const float*)d_in[7];
  const float* mlp_w1 = (const float*)d_in[8];
  const float* mlp_b1 = (const float*)d_in[9];
  const float* mlp_w2 = (const float*)d_in[10];
  const float* mlp_b2 = (const float*)d_in[11];
  const float* gin_eps= (const float*)d_in[12];
  const float* ln1_g  = (const float*)d_in[13];
  const float* ln1_b  = (const float*)d_in[14];
  const float* attn_in_w = (const float*)d_in[15];
  const float* attn_in_b = (const float*)d_in[16];
  const float* attn_out_w= (const float*)d_in[17];
  const float* attn_out_b= (const float*)d_in[18];
  const float* ln2_g  = (const float*)d_in[19];
  const float* ln2_b  = (const float*)d_in[20];
  const float* ffn_w1 = (const float*)d_in[21];
  const float* ffn_b1 = (const float*)d_in[22];
  const float* ffn_w2 = (const float*)d_in[23];
  const float* ffn_b2 = (const float*)d_in[24];
  const float* ln3_g  = (const float*)d_in[25];
  const float* ln3_b  = (const float*)d_in[26];

  float* ws = (float*)d_ws;
  float* x   = ws;                                  // [NN,256]   1048576 f
  float* tb  = x   + (size_t)NN * DIM;              // [NN,768]   3145728 f
  float* t2  = tb  + (size_t)NN * 768;              // [NN,256]   1048576 f
  float* att = t2  + (size_t)NN * DIM;              // [NN,256]
  float* agg = att + (size_t)NN * DIM;              // [NN,256]
  float* he  = agg + (size_t)NN * DIM;              // [NN,128]   524288 f
  int* counts = (int*)(he + (size_t)NN * 128);
  int* offs   = counts + NN;       // NN+1
  int* cursor = offs + NN + 1;
  int* esrc   = cursor + NN;       // NE

  // aliased bf16 buffers (dead regions during attention phase):
  // qkvb = 4096*768*2B = 6 MB  -> exactly spans agg (4MB) + he (2MB)
  // VT   = 8*32*4096*2B = 2 MB -> lives in t2 (4MB)
  unsigned short* qkvb = (unsigned short*)agg;
  unsigned short* VT   = (unsigned short*)t2;

  // CSR build (edges identical for both layers)
  zero_counts<<<16, 256, 0, stream>>>(counts);
  count_edges<<<NE / 256, 256, 0, stream>>>(ei, counts);
  scan_offsets<<<1, 1024, 0, stream>>>(counts, offs, cursor);
  scatter_edges<<<NE / 256, 256, 0, stream>>>(ei, cursor, esrc);

  // input projection: x = elu(x_in @ in_w^T + in_b)   [4096,72] -> [4096,256]
  gemm_bias_act<1><<<dim3(DIM/64, NN/64), 256, 0, stream>>>(x_in, in_w, in_b, x, NN, DIM, 72);

  for (int l = 0; l < 2; l++) {
    // GIN
    gin_agg<<<NN, 256, 0, stream>>>(offs, esrc, x, gin_eps, l, agg);
    gemm_bias_act<1><<<dim3(4, 64), 256, 0, stream>>>(agg, mlp_w1 + (size_t)l*DIM*DIM,
                                                      mlp_b1 + l*DIM, tb, NN, DIM, DIM);
    gemm_bias_act<0><<<dim3(4, 64), 256, 0, stream>>>(tb, mlp_w2 + (size_t)l*DIM*DIM,
                                                      mlp_b2 + l*DIM, t2, NN, DIM, DIM);
    ln_act_add<1><<<NN, 256, 0, stream>>>(t2, ln1_g + l*DIM, ln1_b + l*DIM, x);

    // attention: qkv GEMM (f32) -> bf16 convert + V transpose -> MFMA flash
    gemm_bias_act<0><<<dim3(12, 64), 256, 0, stream>>>(x, attn_in_w + (size_t)l*768*DIM,
                                                       attn_in_b + l*768, tb, NN, 768, DIM);
    qkv_convert<<<NN, 256, 0, stream>>>(tb, qkvb);
    vt_transpose<<<dim3(32, 8), 256, 0, stream>>>(tb, VT);
    attn_mfma<<<dim3(64, 8), 256, 0, stream>>>(qkvb, VT, att);
    gemm_bias_act<0><<<dim3(4, 64), 256, 0, stream>>>(att, attn_out_w + (size_t)l*DIM*DIM,
                                                      attn_out_b + l*DIM, t2, NN, DIM, DIM);
    ln_act_add<0><<<NN, 256, 0, stream>>>(t2, ln2_g + l*DIM, ln2_b + l*DIM, x);

    // FFN
    gemm_bias_act<2><<<dim3(8, 64), 256, 0, stream>>>(x, ffn_w1 + (size_t)l*512*DIM,
                                                      ffn_b1 + l*512, tb, NN, 512, DIM);
    gemm_bias_act<0><<<dim3(4, 64), 256, 0, stream>>>(tb, ffn_w2 + (size_t)l*DIM*512,
                                                      ffn_b2 + l*DIM, t2, NN, DIM, 512);
    ln_act_add<0><<<NN, 256, 0, stream>>>(t2, ln3_g + l*DIM, ln3_b + l*DIM, x);
  }

  // head
  gemm_bias_act<1><<<dim3(2, 64), 256, 0, stream>>>(x, head_w1, head_b1, he, NN, 128, DIM);
  head2_kernel<<<(NN * 5 + 255) / 256, 256, 0, stream>>>(he, head_w2, head_b2, (float*)d_out);
}

// Round 3
// 472.330 us; speedup vs baseline: 16.3937x; 1.4313x over previous
//
#include <hip/hip_runtime.h>
#include <math.h>

#define NN 4096
#define NE 131072
#define DIM 256
#define NHEAD 8
#define HD 32

typedef __attribute__((ext_vector_type(8))) short short8v;
typedef __attribute__((ext_vector_type(4))) float f32x4;
#define MFMA16(a, b, c) __builtin_amdgcn_mfma_f32_16x16x32_bf16(a, b, c, 0, 0, 0)

__device__ __forceinline__ float elu_f(float v){ return v > 0.f ? v : expm1f(v); }
__device__ __forceinline__ float gelu_f(float v){
  const float c = 0.7978845608028654f;
  float t = tanhf(c * (v + 0.044715f * v * v * v));
  return 0.5f * v * (1.f + t);
}
__device__ __forceinline__ unsigned short f2bf(float f) {
  unsigned int u = __builtin_bit_cast(unsigned int, f);
  u += 0x7FFFu + ((u >> 16) & 1u);
  return (unsigned short)(u >> 16);
}

// ---------------- CSR build ----------------
__global__ void zero_counts(int* __restrict__ counts) {
  int i = blockIdx.x * 256 + threadIdx.x;
  if (i < NN) counts[i] = 0;
}

__global__ void count_edges(const int* __restrict__ ei, int* __restrict__ counts) {
  int e = blockIdx.x * 256 + threadIdx.x;
  if (e < NE) atomicAdd(&counts[ei[NE + e]], 1);
}

__global__ __launch_bounds__(1024) void scan_offsets(const int* __restrict__ counts,
                                                     int* __restrict__ offs,
                                                     int* __restrict__ cursor) {
  __shared__ int tmp[1024];
  int t = threadIdx.x;
  int base = t * 4;
  int c0 = counts[base], c1 = counts[base+1], c2 = counts[base+2], c3 = counts[base+3];
  int tsum = c0 + c1 + c2 + c3;
  tmp[t] = tsum;
  __syncthreads();
  for (int d = 1; d < 1024; d <<= 1) {
    int v = (t >= d) ? tmp[t - d] : 0;
    __syncthreads();
    tmp[t] += v;
    __syncthreads();
  }
  int excl = tmp[t] - tsum;
  offs[base]   = excl;           cursor[base]   = excl;
  offs[base+1] = excl + c0;      cursor[base+1] = excl + c0;
  offs[base+2] = excl + c0 + c1; cursor[base+2] = excl + c0 + c1;
  offs[base+3] = excl + c0 + c1 + c2; cursor[base+3] = excl + c0 + c1 + c2;
  if (t == 1023) offs[NN] = tmp[1023];
}

__global__ void scatter_edges(const int* __restrict__ ei, int* __restrict__ cursor,
                              int* __restrict__ esrc) {
  int e = blockIdx.x * 256 + threadIdx.x;
  if (e < NE) {
    int d = ei[NE + e];
    int pos = atomicAdd(&cursor[d], 1);
    esrc[pos] = ei[e];
  }
}

// block per node: aggb[n][c] = bf16( (1+eps)*x[n][c] + sum_{e} x[src_e][c] )
__global__ __launch_bounds__(256) void gin_agg(const int* __restrict__ offs,
                                               const int* __restrict__ esrc,
                                               const float* __restrict__ x,
                                               const float* __restrict__ eps_p, int l,
                                               unsigned short* __restrict__ aggb) {
  int n = blockIdx.x, c = threadIdx.x;
  int e0 = offs[n], e1 = offs[n + 1];
  float acc = 0.f;
  for (int e = e0; e < e1; e++) acc += x[(size_t)esrc[e] * DIM + c];
  float eps = eps_p[l];
  aggb[(size_t)n * DIM + c] = f2bf((1.f + eps) * x[(size_t)n * DIM + c] + acc);
}

// ---------------- bf16 MFMA GEMM: C = act(A @ W^T + bias) ----------------
// A [M,K] bf16 row-major, W [N,K] bf16 row-major. M,N mult of 64, K mult of 32.
// ACT: 0 none, 1 elu, 2 gelu. WF32/WBF16: write f32 / bf16 outputs. QSCALE: scale cols<256.
template<int ACT, int WF32, int WBF16, int QSCALE>
__global__ __launch_bounds__(256) void gemm_mfma(
    const unsigned short* __restrict__ A, const unsigned short* __restrict__ W,
    const float* __restrict__ bias, float* __restrict__ Cf,
    unsigned short* __restrict__ Cb, int M, int N, int K)
{
  __shared__ __align__(16) unsigned short As[64][40];   // stride 80B: 2-way banks (free)
  __shared__ __align__(16) unsigned short Ws[64][40];
  int t = threadIdx.x;
  int w = t >> 6, lane = t & 63, lo = lane & 15, g = lane >> 4;
  int wr = w >> 1, wc = w & 1;
  int bn = blockIdx.x * 64, bm = blockIdx.y * 64;
  int srow = t >> 2, skk = (t & 3) << 3;
  const unsigned short* ap = A + (size_t)(bm + srow) * K + skk;
  const unsigned short* wp = W + (size_t)(bn + srow) * K + skk;

  f32x4 acc[2][2] = {{{0.f,0.f,0.f,0.f},{0.f,0.f,0.f,0.f}},
                     {{0.f,0.f,0.f,0.f},{0.f,0.f,0.f,0.f}}};

  for (int k0 = 0; k0 < K; k0 += 32) {
    *(short8v*)&As[srow][skk] = *(const short8v*)(ap + k0);
    *(short8v*)&Ws[srow][skk] = *(const short8v*)(wp + k0);
    __syncthreads();
    short8v a0 = *(const short8v*)&As[wr * 32 + lo][8 * g];
    short8v a1 = *(const short8v*)&As[wr * 32 + 16 + lo][8 * g];
    short8v b0 = *(const short8v*)&Ws[wc * 32 + lo][8 * g];
    short8v b1 = *(const short8v*)&Ws[wc * 32 + 16 + lo][8 * g];
    acc[0][0] = MFMA16(a0, b0, acc[0][0]);
    acc[0][1] = MFMA16(a0, b1, acc[0][1]);
    acc[1][0] = MFMA16(a1, b0, acc[1][0]);
    acc[1][1] = MFMA16(a1, b1, acc[1][1]);
    __syncthreads();
  }

  #pragma unroll
  for (int mi = 0; mi < 2; mi++) {
    #pragma unroll
    for (int ni = 0; ni < 2; ni++) {
      #pragma unroll
      for (int r = 0; r < 4; r++) {
        int row = bm + wr * 32 + mi * 16 + 4 * g + r;
        int col = bn + wc * 32 + ni * 16 + lo;
        float v = acc[mi][ni][r] + bias[col];
        if (ACT == 1) v = elu_f(v);
        if (ACT == 2) v = gelu_f(v);
        if (QSCALE) { if (col < 256) v *= 0.17677669529663687f; }
        if (WF32) Cf[(size_t)row * N + col] = v;
        if (WBF16) Cb[(size_t)row * N + col] = f2bf(v);
      }
    }
  }
}

// ---------------- LayerNorm(+act) + residual add; also emits bf16 copy ----------------
template<int ACT>
__global__ __launch_bounds__(256) void ln_act_add(const float* __restrict__ in,
                                                  const float* __restrict__ g,
                                                  const float* __restrict__ b,
                                                  float* __restrict__ x,
                                                  unsigned short* __restrict__ xb) {
  int rowb = blockIdx.x;
  int c = threadIdx.x;
  float v = in[(size_t)rowb * DIM + c];
  float s = v, s2 = v * v;
  #pragma unroll
  for (int off = 32; off >= 1; off >>= 1) {
    s  += __shfl_xor(s,  off, 64);
    s2 += __shfl_xor(s2, off, 64);
  }
  __shared__ float ws1[4], ws2[4];
  int w = threadIdx.x >> 6, lane = threadIdx.x & 63;
  if (lane == 0) { ws1[w] = s; ws2[w] = s2; }
  __syncthreads();
  s  = ws1[0] + ws1[1] + ws1[2] + ws1[3];
  s2 = ws2[0] + ws2[1] + ws2[2] + ws2[3];
  float mean = s * (1.f / DIM);
  float var = s2 * (1.f / DIM) - mean * mean;
  float r = rsqrtf(var + 1e-5f);
  float o = (v - mean) * r * g[c] + b[c];
  if (ACT == 1) o = elu_f(o);
  float nx = x[(size_t)rowb * DIM + c] + o;
  x[(size_t)rowb * DIM + c] = nx;
  xb[(size_t)rowb * DIM + c] = f2bf(nx);
}

// ---------------- V transpose: tbb[:,512+h*32+d] (bf16) -> VT[h*32+d][n] ----------------
__global__ __launch_bounds__(256) void vt_transpose(const unsigned short* __restrict__ tbb,
                                                    unsigned short* __restrict__ VT) {
  __shared__ unsigned short lds[128][33];
  int h = blockIdx.y;
  int nb = blockIdx.x * 128;
  int tid = threadIdx.x;
  int r8 = tid >> 5, d = tid & 31;
  #pragma unroll
  for (int i = 0; i < 16; i++) {
    int n = i * 8 + r8;
    lds[n][d] = tbb[(size_t)(nb + n) * 768 + 512 + h * 32 + d];
  }
  __syncthreads();
  int dd = tid >> 7, j = tid & 127;
  #pragma unroll
  for (int i = 0; i < 16; i++) {
    int d2 = i * 2 + dd;
    VT[((size_t)h * 32 + d2) * 4096 + nb + j] = lds[j][d2];
  }
}

// P-tile LDS swizzle: 128B rows, XOR 16B-granule index with q&7
__device__ __forceinline__ int pswz(int q, int col) {
  return (col & 7) | ((((col >> 3) ^ q) & 7) << 3);
}

// ---------------- MFMA flash attention ----------------
// tbb [NN][768] bf16 (Q pre-scaled), VT [8*32][NN] bf16, out attb [NN][256] bf16
__global__ __launch_bounds__(256) void attn_mfma(const unsigned short* __restrict__ qkvb,
                                                 const unsigned short* __restrict__ VT,
                                                 unsigned short* __restrict__ attb) {
  __shared__ __align__(16) unsigned short plds[4][16][64];
  int tid = threadIdx.x;
  int w = tid >> 6, lane = tid & 63;
  int lo = lane & 15, g = lane >> 4;
  int h = blockIdx.y;
  int qb = blockIdx.x * 64 + w * 16;

  short8v qf = *(const short8v*)(qkvb + (size_t)(qb + lo) * 768 + h * 32 + 8 * g);

  f32x4 acc0 = {0.f, 0.f, 0.f, 0.f};
  f32x4 acc1 = {0.f, 0.f, 0.f, 0.f};
  float mr[4] = {-1e30f, -1e30f, -1e30f, -1e30f};
  float lr[4] = {0.f, 0.f, 0.f, 0.f};

  const unsigned short* Kb = qkvb + 256 + h * 32 + 8 * g;
  const unsigned short* Vb = VT + (size_t)h * 32 * 4096 + 8 * g;
  const f32x4 zf = {0.f, 0.f, 0.f, 0.f};

  for (int kb = 0; kb < NN; kb += 64) {
    short8v kf0 = *(const short8v*)(Kb + (size_t)(kb +  0 + lo) * 768);
    short8v kf1 = *(const short8v*)(Kb + (size_t)(kb + 16 + lo) * 768);
    short8v kf2 = *(const short8v*)(Kb + (size_t)(kb + 32 + lo) * 768);
    short8v kf3 = *(const short8v*)(Kb + (size_t)(kb + 48 + lo) * 768);
    f32x4 s0 = MFMA16(qf, kf0, zf);
    f32x4 s1 = MFMA16(qf, kf1, zf);
    f32x4 s2 = MFMA16(qf, kf2, zf);
    f32x4 s3 = MFMA16(qf, kf3, zf);

    #pragma unroll
    for (int r = 0; r < 4; r++) {
      float t = fmaxf(fmaxf(s0[r], s1[r]), fmaxf(s2[r], s3[r]));
      t = fmaxf(t, __shfl_xor(t, 1, 64));
      t = fmaxf(t, __shfl_xor(t, 2, 64));
      t = fmaxf(t, __shfl_xor(t, 4, 64));
      t = fmaxf(t, __shfl_xor(t, 8, 64));
      float nm = fmaxf(mr[r], t);
      float f = __expf(mr[r] - nm);
      mr[r] = nm;
      float p0 = __expf(s0[r] - nm), p1 = __expf(s1[r] - nm);
      float p2 = __expf(s2[r] - nm), p3 = __expf(s3[r] - nm);
      lr[r] = lr[r] * f + (p0 + p1 + p2 + p3);
      acc0[r] *= f; acc1[r] *= f;
      int q = 4 * g + r;
      plds[w][q][pswz(q, lo)]      = f2bf(p0);
      plds[w][q][pswz(q, lo + 16)] = f2bf(p1);
      plds[w][q][pswz(q, lo + 32)] = f2bf(p2);
      plds[w][q][pswz(q, lo + 48)] = f2bf(p3);
    }

    short8v pa0 = *(const short8v*)&plds[w][lo][pswz(lo, 8 * g)];
    short8v pa1 = *(const short8v*)&plds[w][lo][pswz(lo, 32 + 8 * g)];
    short8v vf00 = *(const short8v*)(Vb + (size_t)(lo)      * 4096 + kb);
    short8v vf01 = *(const short8v*)(Vb + (size_t)(lo)      * 4096 + kb + 32);
    short8v vf10 = *(const short8v*)(Vb + (size_t)(lo + 16) * 4096 + kb);
    short8v vf11 = *(const short8v*)(Vb + (size_t)(lo + 16) * 4096 + kb + 32);
    acc0 = MFMA16(pa0, vf00, acc0);
    acc0 = MFMA16(pa1, vf01, acc0);
    acc1 = MFMA16(pa0, vf10, acc1);
    acc1 = MFMA16(pa1, vf11, acc1);
  }

  #pragma unroll
  for (int r = 0; r < 4; r++) {
    float t = lr[r];
    t += __shfl_xor(t, 1, 64);
    t += __shfl_xor(t, 2, 64);
    t += __shfl_xor(t, 4, 64);
    t += __shfl_xor(t, 8, 64);
    float inv = 1.f / t;
    int q = qb + 4 * g + r;
    attb[(size_t)q * DIM + h * 32 + lo]      = f2bf(acc0[r] * inv);
    attb[(size_t)q * DIM + h * 32 + 16 + lo] = f2bf(acc1[r] * inv);
  }
}

// ---------------- weight conversion (all weight buffers -> bf16 arena) ----------------
#define WO0 0
#define WO1 131072
#define WO2 262144
#define WO3 655360
#define WO4 786432
#define WO5 1048576
#define WO6 1310720
#define WTOT 1343488
__global__ __launch_bounds__(256) void wconv(const float* __restrict__ s0, const float* __restrict__ s1,
                                             const float* __restrict__ s2, const float* __restrict__ s3,
                                             const float* __restrict__ s4, const float* __restrict__ s5,
                                             const float* __restrict__ s6, unsigned short* __restrict__ dst) {
  int i4 = (blockIdx.x * 256 + threadIdx.x) * 4;
  if (i4 >= WTOT) return;
  const float* src; int loc;
  if      (i4 < WO1) { src = s0; loc = i4 - WO0; }
  else if (i4 < WO2) { src = s1; loc = i4 - WO1; }
  else if (i4 < WO3) { src = s2; loc = i4 - WO2; }
  else if (i4 < WO4) { src = s3; loc = i4 - WO3; }
  else if (i4 < WO5) { src = s4; loc = i4 - WO4; }
  else if (i4 < WO6) { src = s5; loc = i4 - WO5; }
  else               { src = s6; loc = i4 - WO6; }
  float4 v = *(const float4*)(src + loc);
  ushort4 o;
  o.x = f2bf(v.x); o.y = f2bf(v.y); o.z = f2bf(v.z); o.w = f2bf(v.w);
  *(ushort4*)(dst + i4) = o;
}

// pad-convert [rows][72] f32 -> [rows][96] bf16 (zero pad)
__global__ __launch_bounds__(256) void pad72_96(const float* __restrict__ src,
                                                unsigned short* __restrict__ dst, int total) {
  int idx = blockIdx.x * 256 + threadIdx.x;
  if (idx >= total) return;
  int row = idx / 96, col = idx - row * 96;
  dst[idx] = (col < 72) ? f2bf(src[row * 72 + col]) : (unsigned short)0;
}

// ---------------- tiny head: out[4096,5] ----------------
__global__ void head2_kernel(const float* __restrict__ e, const float* __restrict__ w,
                             const float* __restrict__ b, float* __restrict__ out) {
  int idx = blockIdx.x * 256 + threadIdx.x;
  if (idx >= NN * 5) return;
  int rowi = idx / 5, col = idx % 5;
  float s = b[col];
  const float* ep = e + (size_t)rowi * 128;
  const float* wp = w + (size_t)col * 128;
  #pragma unroll 16
  for (int k = 0; k < 128; k++) s += ep[k] * wp[k];
  out[idx] = s;
}

extern "C" void kernel_launch(void* const* d_in, const int* in_sizes, int n_in,
                              void* d_out, int out_size, void* d_ws, size_t ws_size,
                              hipStream_t stream) {
  const float* x_in   = (const float*)d_in[0];
  const int*   ei     = (const int*)  d_in[1];
  const float* in_w   = (const float*)d_in[2];
  const float* in_b   = (const float*)d_in[3];
  const float* head_w1= (const float*)d_in[4];
  const float* head_b1= (const float*)d_in[5];
  const float* head_w2= (const float*)d_in[6];
  const float* head_b2= (const float*)d_in[7];
  const float* mlp_w1 = (const float*)d_in[8];
  const float* mlp_b1 = (const float*)d_in[9];
  const float* mlp_w2 = (const float*)d_in[10];
  const float* mlp_b2 = (const float*)d_in[11];
  const float* gin_eps= (const float*)d_in[12];
  const float* ln1_g  = (const float*)d_in[13];
  const float* ln1_b  = (const float*)d_in[14];
  const float* attn_in_w = (const float*)d_in[15];
  const float* attn_in_b = (const float*)d_in[16];
  const float* attn_out_w= (const float*)d_in[17];
  const float* attn_out_b= (const float*)d_in[18];
  const float* ln2_g  = (const float*)d_in[19];
  const float* ln2_b  = (const float*)d_in[20];
  const float* ffn_w1 = (const float*)d_in[21];
  const float* ffn_b1 = (const float*)d_in[22];
  const float* ffn_w2 = (const float*)d_in[23];
  const float* ffn_b2 = (const float*)d_in[24];
  const float* ln3_g  = (const float*)d_in[25];
  const float* ln3_b  = (const float*)d_in[26];

  float* ws = (float*)d_ws;
  float* x    = ws;                              // [NN,256] f32
  float* t2   = x  + (size_t)NN * DIM;           // [NN,256] f32
  float* he   = t2 + (size_t)NN * DIM;           // [NN,128] f32
  unsigned short* xb   = (unsigned short*)(he + (size_t)NN * 128);
  unsigned short* tbb  = xb   + (size_t)NN * DIM;       // [NN,768] bf16 (qkv / hidden)
  unsigned short* aggb = tbb  + (size_t)NN * 768;       // [NN,256] bf16
  unsigned short* attb = aggb + (size_t)NN * DIM;       // [NN,256] bf16
  unsigned short* VT   = attb + (size_t)NN * DIM;       // [256][NN] bf16
  unsigned short* xinb = VT   + (size_t)NN * DIM;       // [NN][96] bf16
  unsigned short* inwb = xinb + (size_t)NN * 96;        // [256][96] bf16
  unsigned short* warena = inwb + 256 * 96;             // WTOT bf16
  int* counts = (int*)(warena + WTOT);
  int* offs   = counts + NN;       // NN+1
  int* cursor = offs + NN + 1;
  int* esrc   = cursor + NN;       // NE

  const unsigned short* w_mlp1 = warena + WO0;
  const unsigned short* w_mlp2 = warena + WO1;
  const unsigned short* w_qkv  = warena + WO2;
  const unsigned short* w_aout = warena + WO3;
  const unsigned short* w_ffn1 = warena + WO4;
  const unsigned short* w_ffn2 = warena + WO5;
  const unsigned short* w_h1   = warena + WO6;

  // CSR build
  zero_counts<<<16, 256, 0, stream>>>(counts);
  count_edges<<<NE / 256, 256, 0, stream>>>(ei, counts);
  scan_offsets<<<1, 1024, 0, stream>>>(counts, offs, cursor);
  scatter_edges<<<NE / 256, 256, 0, stream>>>(ei, cursor, esrc);

  // weight + input conversions
  wconv<<<1312, 256, 0, stream>>>(mlp_w1, mlp_w2, attn_in_w, attn_out_w, ffn_w1, ffn_w2,
                                  head_w1, warena);
  pad72_96<<<(NN * 96 + 255) / 256, 256, 0, stream>>>(x_in, xinb, NN * 96);
  pad72_96<<<(256 * 96 + 255) / 256, 256, 0, stream>>>(in_w, inwb, 256 * 96);

  // input projection: x,xb = elu(x_in @ in_w^T + in_b)
  gemm_mfma<1,1,1,0><<<dim3(DIM/64, NN/64), 256, 0, stream>>>(xinb, inwb, in_b, x, xb,
                                                              NN, DIM, 96);

  for (int l = 0; l < 2; l++) {
    // GIN
    gin_agg<<<NN, 256, 0, stream>>>(offs, esrc, x, gin_eps, l, aggb);
    gemm_mfma<1,0,1,0><<<dim3(4, 64), 256, 0, stream>>>(aggb, w_mlp1 + (size_t)l*65536,
                                                        mlp_b1 + l*DIM, nullptr, tbb,
                                                        NN, DIM, DIM);
    gemm_mfma<0,1,0,0><<<dim3(4, 64), 256, 0, stream>>>(tbb, w_mlp2 + (size_t)l*65536,
                                                        mlp_b2 + l*DIM, t2, nullptr,
                                                        NN, DIM, DIM);
    ln_act_add<1><<<NN, 256, 0, stream>>>(t2, ln1_g + l*DIM, ln1_b + l*DIM, x, xb);

    // attention
    gemm_mfma<0,0,1,1><<<dim3(12, 64), 256, 0, stream>>>(xb, w_qkv + (size_t)l*196608,
                                                         attn_in_b + l*768, nullptr, tbb,
                                                         NN, 768, DIM);
    vt_transpose<<<dim3(32, 8), 256, 0, stream>>>(tbb, VT);
    attn_mfma<<<dim3(64, 8), 256, 0, stream>>>(tbb, VT, attb);
    gemm_mfma<0,1,0,0><<<dim3(4, 64), 256, 0, stream>>>(attb, w_aout + (size_t)l*65536,
                                                        attn_out_b + l*DIM, t2, nullptr,
                                                        NN, DIM, DIM);
    ln_act_add<0><<<NN, 256, 0, stream>>>(t2, ln2_g + l*DIM, ln2_b + l*DIM, x, xb);

    // FFN
    gemm_mfma<2,0,1,0><<<dim3(8, 64), 256, 0, stream>>>(xb, w_ffn1 + (size_t)l*131072,
                                                        ffn_b1 + l*512, nullptr, tbb,
                                                        NN, 512, DIM);
    gemm_mfma<0,1,0,0><<<dim3(4, 64), 256, 0, stream>>>(tbb, w_ffn2 + (size_t)l*131072,
                                                        ffn_b2 + l*DIM, t2, nullptr,
                                                        NN, DIM, 512);
    ln_act_add<0><<<NN, 256, 0, stream>>>(t2, ln3_g + l*DIM, ln3_b + l*DIM, x, xb);
  }

  // head
  gemm_mfma<1,1,0,0><<<dim3(2, 64), 256, 0, stream>>>(xb, w_h1, head_b1, he, nullptr,
                                                      NN, 128, DIM);
  head2_kernel<<<(NN * 5 + 255) / 256, 256, 0, stream>>>(he, head_w2, head_b2, (float*)d_out);
}